// Round 1
// baseline (434.548 us; speedup 1.0000x reference)
//
#include <hip/hip_runtime.h>
#include <stdint.h>

#define BATCH 8
#define SEQ   2048
#define DIM   512

typedef __attribute__((ext_vector_type(8)))  short short8;    // 8 bf16 operand (4 VGPRs)
typedef __attribute__((ext_vector_type(16))) float floatx16;  // 32x32 C/D frag

// ---- LDS map for main kernel, in u16 elements ----
// PV phase : Vt [512][24]  at 0      (12288)
// QK phase : Qc [64][72]   at 0      (4608) ; Kc [256][72] at 4608 (ends 23040)
// P        : [64][264]     at 12288  (ends 29184)  -- written after QK, read in PV
#define VT_OFF 0
#define QC_OFF 0
#define KC_OFF 4608
#define P_OFF  12288
#define SMEM_U16 29184

static __device__ __forceinline__ unsigned short f32_bf16(float f) {
  unsigned u = __builtin_bit_cast(unsigned, f);
  u += 0x7FFFu + ((u >> 16) & 1u);          // round-to-nearest-even
  return (unsigned short)(u >> 16);
}
static __device__ __forceinline__ short8 ld_frag(const unsigned short* p) {
  return __builtin_bit_cast(short8, *reinterpret_cast<const uint4*>(p));
}

// ---------------- prep: norms -> xn (bf16 row-major), x -> xT (bf16, j-blocked) ---------------
// grid 512 = 8 batches x 64 j-blocks of 32 rows ; 256 threads
__global__ __launch_bounds__(256) void prep_kernel(const float* __restrict__ x,
                                                   unsigned short* __restrict__ xn,
                                                   unsigned short* __restrict__ xt) {
  const int b  = blockIdx.x >> 6;
  const int jb = blockIdx.x & 63;
  const int t  = threadIdx.x;
  const int j  = t >> 3;   // 0..31 row in tile
  const int s  = t & 7;    // 0..7  d-octant (64 elems)

  __shared__ unsigned short xs[32 * 516];   // bf16(x) tile, stride 516 breaks bank alignment
  __shared__ float rsum[32][8];
  __shared__ float scl[32];

  const long rowg = ((long)b * SEQ + (long)jb * 32 + j) * DIM;
  float vals[64];
  float acc = 0.f;
  const float4* xv = reinterpret_cast<const float4*>(x + rowg + s * 64);
#pragma unroll
  for (int k = 0; k < 16; ++k) {
    float4 v = xv[k];
    vals[4*k+0] = v.x; vals[4*k+1] = v.y; vals[4*k+2] = v.z; vals[4*k+3] = v.w;
    acc += v.x*v.x + v.y*v.y + v.z*v.z + v.w*v.w;
    ushort4 pk;
    pk.x = f32_bf16(v.x); pk.y = f32_bf16(v.y); pk.z = f32_bf16(v.z); pk.w = f32_bf16(v.w);
    *reinterpret_cast<ushort4*>(&xs[j * 516 + s * 64 + 4 * k]) = pk;
  }
  rsum[j][s] = acc;
  __syncthreads();
  if (t < 32) {
    float a = 0.f;
#pragma unroll
    for (int k = 0; k < 8; ++k) a += rsum[t][k];
    scl[t] = 1.f / (sqrtf(a) + 1e-12f);
  }
  __syncthreads();
  const float sc = scl[j];
  unsigned short* xnp = xn + rowg + s * 64;
#pragma unroll
  for (int k = 0; k < 16; ++k) {
    ushort4 pk;
    pk.x = f32_bf16(vals[4*k+0] * sc);
    pk.y = f32_bf16(vals[4*k+1] * sc);
    pk.z = f32_bf16(vals[4*k+2] * sc);
    pk.w = f32_bf16(vals[4*k+3] * sc);
    *reinterpret_cast<ushort4*>(xnp + 4 * k) = pk;
  }
  // xT blocked: layout [b][jblk=jb][d][32 j]; fully coalesced 16B writes
  unsigned short* xtb = xt + (((long)b * 64 + jb) * DIM) * 32;
  for (int u = t; u < DIM * 4; u += 256) {
    const int d = u >> 2, jq = u & 3;
    unsigned short tmp[8];
#pragma unroll
    for (int r = 0; r < 8; ++r) tmp[r] = xs[(jq * 8 + r) * 516 + d];
    uint4 o;
    o.x = (unsigned)tmp[0] | ((unsigned)tmp[1] << 16);
    o.y = (unsigned)tmp[2] | ((unsigned)tmp[3] << 16);
    o.z = (unsigned)tmp[4] | ((unsigned)tmp[5] << 16);
    o.w = (unsigned)tmp[6] | ((unsigned)tmp[7] << 16);
    *reinterpret_cast<uint4*>(xtb + d * 32 + jq * 8) = o;
  }
}

// ---------------- main: flash-style fused attention, fixed softmax shift = 1 ----------------
// grid 256 = 8 batches (bid&7, XCD-locality) x 32 q-tiles of 64 rows ; 256 threads = 4 waves
__global__ __launch_bounds__(256, 1) void qattn_kernel(const unsigned short* __restrict__ xn,
                                                       const unsigned short* __restrict__ xt,
                                                       float* __restrict__ out) {
  const int b    = blockIdx.x & 7;
  const int qt   = blockIdx.x >> 3;
  const int q0   = qt * 64;
  const int tid  = threadIdx.x;
  const int w    = tid >> 6;        // wave 0..3
  const int lane = tid & 63;
  const int ln   = lane & 31;       // m/n index inside 32-tile
  const int half = lane >> 5;       // k-half
  const int k8   = half * 8;

  __shared__ unsigned short smem[SMEM_U16];
  __shared__ float lsum[64];
  if (tid < 64) lsum[tid] = 0.f;

  const unsigned short* xnb = xn + (long)b * SEQ * DIM;
  const unsigned short* xtb = xt + (long)b * 64 * DIM * 32;

  floatx16 zero16;
#pragma unroll
  for (int i = 0; i < 16; ++i) zero16[i] = 0.f;

  floatx16 o_acc[2][4];   // [mt][dtl] : rows mt*32.., cols w*128 + dtl*32..
  floatx16 l_acc[2];
#pragma unroll
  for (int mt = 0; mt < 2; ++mt) {
    l_acc[mt] = zero16;
#pragma unroll
    for (int dt = 0; dt < 4; ++dt) o_acc[mt][dt] = zero16;
  }
  short8 ones;
#pragma unroll
  for (int i = 0; i < 8; ++i) ones[i] = (short)0x3F80;   // bf16 1.0

  uint4 qk_reg[10];   // 2 Qc + 8 Kc 16B units per thread
  uint4 vt_reg[4];

  auto load_qk = [&](int jt, int dc) {
    const int d0 = dc * 64;
#pragma unroll
    for (int k = 0; k < 2; ++k) {          // Qc 64x64
      int u = tid + k * 256, row = u >> 3, h = u & 7;
      qk_reg[k] = *reinterpret_cast<const uint4*>(xnb + (long)(q0 + row) * DIM + d0 + h * 8);
    }
#pragma unroll
    for (int k = 0; k < 8; ++k) {          // Kc 256x64
      int u = tid + k * 256, row = u >> 3, h = u & 7;
      qk_reg[2 + k] = *reinterpret_cast<const uint4*>(xnb + (long)(jt * 256 + row) * DIM + d0 + h * 8);
    }
  };
  auto store_qk = [&]() {
#pragma unroll
    for (int k = 0; k < 2; ++k) {
      int u = tid + k * 256, row = u >> 3, h = u & 7;
      *reinterpret_cast<uint4*>(&smem[QC_OFF + row * 72 + h * 8]) = qk_reg[k];
    }
#pragma unroll
    for (int k = 0; k < 8; ++k) {
      int u = tid + k * 256, row = u >> 3, h = u & 7;
      *reinterpret_cast<uint4*>(&smem[KC_OFF + row * 72 + h * 8]) = qk_reg[2 + k];
    }
  };
  auto load_vt = [&](int jt, int ks) {     // one k-step: 16 j-cols, all 512 d
    const int jb2 = jt * 8 + (ks >> 1);
    const int jl0 = (ks & 1) * 16;
#pragma unroll
    for (int k = 0; k < 4; ++k) {
      int u = tid + k * 256, d = u >> 1, h = u & 1;
      vt_reg[k] = *reinterpret_cast<const uint4*>(xtb + ((long)jb2 * DIM + d) * 32 + jl0 + h * 8);
    }
  };
  auto store_vt = [&]() {
#pragma unroll
    for (int k = 0; k < 4; ++k) {
      int u = tid + k * 256, d = u >> 1, h = u & 1;
      *reinterpret_cast<uint4*>(&smem[VT_OFF + d * 24 + h * 8]) = vt_reg[k];
    }
  };

  load_qk(0, 0);
  for (int jt = 0; jt < 8; ++jt) {
    floatx16 s_acc[2][2];
#pragma unroll
    for (int mt = 0; mt < 2; ++mt)
#pragma unroll
      for (int h = 0; h < 2; ++h) s_acc[mt][h] = zero16;

    // ---- QK: S[64][256] = Qn . Kn^T over K=512 in 8 d-chunks of 64 ----
    for (int dc = 0; dc < 8; ++dc) {
      __syncthreads();
      store_qk();
      __syncthreads();
      if (dc < 7) load_qk(jt, dc + 1); else load_vt(jt, 0);
#pragma unroll
      for (int kh = 0; kh < 4; ++kh) {     // 4 k-steps of 16
        short8 af[2], bf[2];
#pragma unroll
        for (int mt = 0; mt < 2; ++mt)
          af[mt] = ld_frag(&smem[QC_OFF + (mt * 32 + ln) * 72 + kh * 16 + k8]);
#pragma unroll
        for (int h = 0; h < 2; ++h)
          bf[h] = ld_frag(&smem[KC_OFF + ((2 * w + h) * 32 + ln) * 72 + kh * 16 + k8]);
#pragma unroll
        for (int mt = 0; mt < 2; ++mt)
#pragma unroll
          for (int h = 0; h < 2; ++h)
            s_acc[mt][h] = __builtin_amdgcn_mfma_f32_32x32x16_bf16(af[mt], bf[h], s_acc[mt][h], 0, 0, 0);
      }
    }
    __syncthreads();   // all K/Q reads finished before P overwrites Kc region

    // ---- P = exp(S^2 - 1), bf16 -> LDS ----
#pragma unroll
    for (int mt = 0; mt < 2; ++mt)
#pragma unroll
      for (int h = 0; h < 2; ++h) {
        const int coln = (2 * w + h) * 32 + ln;
#pragma unroll
        for (int r = 0; r < 16; ++r) {
          float s = s_acc[mt][h][r];
          float p = __expf(__builtin_fmaf(s, s, -1.0f));
          int row = mt * 32 + (r & 3) + 8 * (r >> 2) + 4 * half;
          smem[P_OFF + row * 264 + coln] = f32_bf16(p);
        }
      }

    // ---- PV: O[64][512] += P[64][256] . V[256][512], 16 k-steps of 16 j ----
    for (int ks = 0; ks < 16; ++ks) {
      __syncthreads();
      store_vt();
      __syncthreads();
      if (ks < 15) load_vt(jt, ks + 1);
      else if (jt < 7) load_qk(jt + 1, 0);

      short8 af[2];
#pragma unroll
      for (int mt = 0; mt < 2; ++mt)
        af[mt] = ld_frag(&smem[P_OFF + (mt * 32 + ln) * 264 + ks * 16 + k8]);
#pragma unroll
      for (int dtl = 0; dtl < 4; ++dtl) {
        short8 bfv = ld_frag(&smem[VT_OFF + (w * 128 + dtl * 32 + ln) * 24 + k8]);
#pragma unroll
        for (int mt = 0; mt < 2; ++mt)
          o_acc[mt][dtl] = __builtin_amdgcn_mfma_f32_32x32x16_bf16(af[mt], bfv, o_acc[mt][dtl], 0, 0, 0);
      }
      if ((ks & 3) == w) {   // row-sums l_i via ones-fragment, spread over waves
#pragma unroll
        for (int mt = 0; mt < 2; ++mt)
          l_acc[mt] = __builtin_amdgcn_mfma_f32_32x32x16_bf16(af[mt], ones, l_acc[mt], 0, 0, 0);
      }
    }
  }

  // ---- combine l, divide, store ----
  __syncthreads();
  if (ln == 0) {   // value is uniform across the 32 lanes of each half
#pragma unroll
    for (int mt = 0; mt < 2; ++mt)
#pragma unroll
      for (int r = 0; r < 16; ++r) {
        int row = mt * 32 + (r & 3) + 8 * (r >> 2) + 4 * half;
        atomicAdd(&lsum[row], l_acc[mt][r]);
      }
  }
  __syncthreads();

  float linv[2][16];
#pragma unroll
  for (int mt = 0; mt < 2; ++mt)
#pragma unroll
    for (int r = 0; r < 16; ++r) {
      int row = mt * 32 + (r & 3) + 8 * (r >> 2) + 4 * half;
      linv[mt][r] = 1.0f / lsum[row];
    }

  float* outb = out + (long)b * SEQ * DIM;
#pragma unroll
  for (int mt = 0; mt < 2; ++mt)
#pragma unroll
    for (int dtl = 0; dtl < 4; ++dtl) {
      const int col = w * 128 + dtl * 32 + ln;
#pragma unroll
      for (int r = 0; r < 16; ++r) {
        int row = mt * 32 + (r & 3) + 8 * (r >> 2) + 4 * half;
        outb[(long)(q0 + row) * DIM + col] = o_acc[mt][dtl][r] * linv[mt][r];
      }
    }
}

extern "C" void kernel_launch(void* const* d_in, const int* in_sizes, int n_in,
                              void* d_out, int out_size, void* d_ws, size_t ws_size,
                              hipStream_t stream) {
  const float* x = (const float*)d_in[0];
  float* outp = (float*)d_out;
  unsigned short* xn = (unsigned short*)d_ws;                       // 8*2048*512 bf16 = 16.78 MB
  unsigned short* xt = xn + (size_t)BATCH * SEQ * DIM;              // + 16.78 MB (j-blocked x^T)

  prep_kernel<<<BATCH * (SEQ / 32), 256, 0, stream>>>(x, xn, xt);
  qattn_kernel<<<BATCH * (SEQ / 64), 256, 0, stream>>>(xn, xt, outp);
}

// Round 2
// 176.385 us; speedup vs baseline: 2.4636x; 2.4636x over previous
//
#include <hip/hip_runtime.h>
#include <stdint.h>

#define BATCH 8
#define SEQ   2048
#define DIM   512

typedef __attribute__((ext_vector_type(8)))  short short8;    // 8 bf16 (4 VGPRs)
typedef __attribute__((ext_vector_type(16))) float floatx16;  // 32x32 C/D frag

static __device__ __forceinline__ unsigned short f32_bf16(float f) {
  unsigned u = __builtin_bit_cast(unsigned, f);
  u += 0x7FFFu + ((u >> 16) & 1u);          // round-to-nearest-even
  return (unsigned short)(u >> 16);
}
static __device__ __forceinline__ short8 ld_frag8(const unsigned short* p) {
  return __builtin_bit_cast(short8, *reinterpret_cast<const uint4*>(p));
}
static __device__ __forceinline__ void gld_lds16(const unsigned short* g, unsigned short* l) {
  __builtin_amdgcn_global_load_lds((const __attribute__((address_space(1))) unsigned int*)g,
                                   (__attribute__((address_space(3))) unsigned int*)l, 16, 0, 0);
}
static __device__ __forceinline__ float bf_lo(unsigned u) {
  return __builtin_bit_cast(float, u << 16);
}
static __device__ __forceinline__ float bf_hi(unsigned u) {
  return __builtin_bit_cast(float, u & 0xFFFF0000u);
}

// ---------------- prep: x -> xn (bf16 x-hat, row-major) and xt (bf16 x^T, [b][d][j]) --------
// grid 512 = 8 batches x 64 j-blocks of 32 rows ; 256 threads
__global__ __launch_bounds__(256) void prep_kernel(const float* __restrict__ x,
                                                   unsigned short* __restrict__ xn,
                                                   unsigned short* __restrict__ xt) {
  const int b  = blockIdx.x >> 6;
  const int jb = blockIdx.x & 63;
  const int t  = threadIdx.x;
  const int j  = t >> 3;   // 0..31 row in tile
  const int s  = t & 7;    // 0..7  d-octant (64 elems)

  __shared__ unsigned short xs[32 * 516];   // bf16(x) tile, stride 516
  __shared__ float rsum[32][8];
  __shared__ float scl[32];

  const long rowg = ((long)b * SEQ + (long)jb * 32 + j) * DIM;
  float vals[64];
  float acc = 0.f;
  const float4* xv = reinterpret_cast<const float4*>(x + rowg + s * 64);
#pragma unroll
  for (int k = 0; k < 16; ++k) {
    float4 v = xv[k];
    vals[4*k+0] = v.x; vals[4*k+1] = v.y; vals[4*k+2] = v.z; vals[4*k+3] = v.w;
    acc += v.x*v.x + v.y*v.y + v.z*v.z + v.w*v.w;
    ushort4 pk;
    pk.x = f32_bf16(v.x); pk.y = f32_bf16(v.y); pk.z = f32_bf16(v.z); pk.w = f32_bf16(v.w);
    *reinterpret_cast<ushort4*>(&xs[j * 516 + s * 64 + 4 * k]) = pk;
  }
  rsum[j][s] = acc;
  __syncthreads();
  if (t < 32) {
    float a = 0.f;
#pragma unroll
    for (int k = 0; k < 8; ++k) a += rsum[t][k];
    scl[t] = 1.f / (sqrtf(a) + 1e-12f);
  }
  __syncthreads();
  const float sc = scl[j];
  unsigned short* xnp = xn + rowg + s * 64;
#pragma unroll
  for (int k = 0; k < 16; ++k) {
    ushort4 pk;
    pk.x = f32_bf16(vals[4*k+0] * sc);
    pk.y = f32_bf16(vals[4*k+1] * sc);
    pk.z = f32_bf16(vals[4*k+2] * sc);
    pk.w = f32_bf16(vals[4*k+3] * sc);
    *reinterpret_cast<ushort4*>(xnp + 4 * k) = pk;
  }
  // xt: full transpose [b][d][j]; 16B writes, 64B segments per d-row
  unsigned short* xtb = xt + (long)b * DIM * SEQ;
  for (int u = t; u < DIM * 4; u += 256) {
    const int d = u >> 2, jq = u & 3;
    unsigned short tmp[8];
#pragma unroll
    for (int r = 0; r < 8; ++r) tmp[r] = xs[(jq * 8 + r) * 516 + d];
    uint4 o;
    o.x = (unsigned)tmp[0] | ((unsigned)tmp[1] << 16);
    o.y = (unsigned)tmp[2] | ((unsigned)tmp[3] << 16);
    o.z = (unsigned)tmp[4] | ((unsigned)tmp[5] << 16);
    o.w = (unsigned)tmp[6] | ((unsigned)tmp[7] << 16);
    *reinterpret_cast<uint4*>(xtb + (long)d * SEQ + jb * 32 + jq * 8) = o;
  }
}

// ---------------- gemm1: P[b,i,j] = bf16(exp(S^2 - 1)), S = xn . xn^T  ----------------
// m97 skeleton: 128x128 tile, BK=64, global_load_lds 16B, XOR swizzle
// grid 2048 = 8 batches x 16 i-tiles x 16 j-tiles ; 256 threads = 4 waves
__global__ __launch_bounds__(256, 3) void gemm1_kernel(const unsigned short* __restrict__ xn,
                                                       unsigned short* __restrict__ P) {
  const int b  = blockIdx.x & 7;
  const int t  = blockIdx.x >> 3;
  const int i0 = (t & 15) * 128;
  const int j0 = (t >> 4) * 128;
  const int tid  = threadIdx.x;
  const int w    = tid >> 6;
  const int lane = tid & 63;
  const int ln   = lane & 31;
  const int half = lane >> 5;

  __shared__ __align__(16) unsigned short smem[17408];   // A 8192 | B 8192 ; epilogue P-tile 128x136
  unsigned short* sA = smem;
  unsigned short* sB = smem + 8192;

  const unsigned short* xb = xn + (long)b * SEQ * DIM;
  const unsigned short* Ag = xb + (long)i0 * DIM;
  const unsigned short* Bg = xb + (long)j0 * DIM;

  floatx16 acc[2][2];
#pragma unroll
  for (int mt = 0; mt < 2; ++mt)
#pragma unroll
    for (int nt = 0; nt < 2; ++nt)
#pragma unroll
      for (int i = 0; i < 16; ++i) acc[mt][nt][i] = 0.f;

  const int r0 = (w >> 1) * 64;
  const int c0 = (w & 1) * 64;

  for (int kc = 0; kc < 8; ++kc) {
#pragma unroll
    for (int k = 0; k < 4; ++k) {
      int u = tid + k * 256;
      int row = u >> 3, c = u & 7;
      int gc = (c ^ (row & 7)) * 8;
      gld_lds16(Ag + (long)row * DIM + kc * 64 + gc, sA + u * 8);
      gld_lds16(Bg + (long)row * DIM + kc * 64 + gc, sB + u * 8);
    }
    __syncthreads();
#pragma unroll
    for (int kk = 0; kk < 4; ++kk) {
      const int cc = kk * 2 + half;
      short8 af[2], bf[2];
#pragma unroll
      for (int mt = 0; mt < 2; ++mt) {
        int r = r0 + mt * 32 + ln;
        af[mt] = ld_frag8(sA + r * 64 + (cc ^ (r & 7)) * 8);
      }
#pragma unroll
      for (int nt = 0; nt < 2; ++nt) {
        int r = c0 + nt * 32 + ln;
        bf[nt] = ld_frag8(sB + r * 64 + (cc ^ (r & 7)) * 8);
      }
#pragma unroll
      for (int mt = 0; mt < 2; ++mt)
#pragma unroll
        for (int nt = 0; nt < 2; ++nt)
          acc[mt][nt] = __builtin_amdgcn_mfma_f32_32x32x16_bf16(af[mt], bf[nt], acc[mt][nt], 0, 0, 0);
    }
    __syncthreads();
  }

  // epilogue: p = exp(s^2-1) -> LDS (pitch 136) -> coalesced bf16 stores
  unsigned short* sP = smem;
#pragma unroll
  for (int mt = 0; mt < 2; ++mt)
#pragma unroll
    for (int nt = 0; nt < 2; ++nt) {
      const int col = c0 + nt * 32 + ln;
#pragma unroll
      for (int r = 0; r < 16; ++r) {
        float s = acc[mt][nt][r];
        float p = __expf(__builtin_fmaf(s, s, -1.0f));
        int row = r0 + mt * 32 + (r & 3) + 8 * (r >> 2) + 4 * half;
        sP[row * 136 + col] = f32_bf16(p);
      }
    }
  __syncthreads();
  unsigned short* Pg = P + (long)b * SEQ * SEQ;
#pragma unroll
  for (int k = 0; k < 8; ++k) {
    int u = tid + k * 256;
    int row = u >> 4, c16 = u & 15;
    *reinterpret_cast<uint4*>(Pg + (long)(i0 + row) * SEQ + j0 + c16 * 8) =
        *reinterpret_cast<const uint4*>(sP + row * 136 + c16 * 8);
  }
}

// ---------------- rowsum: l[b*SEQ+i] = sum_j P[b,i,j] ----------------
// grid 4096 : wave per row, 4 rows per block
__global__ __launch_bounds__(256) void rowsum_kernel(const unsigned short* __restrict__ P,
                                                     float* __restrict__ l) {
  const int row  = blockIdx.x * 4 + (threadIdx.x >> 6);
  const int lane = threadIdx.x & 63;
  const unsigned short* pr = P + (long)row * SEQ;
  float s = 0.f;
#pragma unroll
  for (int i = 0; i < 4; ++i) {
    uint4 v = *reinterpret_cast<const uint4*>(pr + (lane + i * 64) * 8);
    s += bf_lo(v.x) + bf_hi(v.x) + bf_lo(v.y) + bf_hi(v.y)
       + bf_lo(v.z) + bf_hi(v.z) + bf_lo(v.w) + bf_hi(v.w);
  }
  s += __shfl_xor(s, 32);
  s += __shfl_xor(s, 16);
  s += __shfl_xor(s, 8);
  s += __shfl_xor(s, 4);
  s += __shfl_xor(s, 2);
  s += __shfl_xor(s, 1);
  if (lane == 0) l[row] = s;
}

// ---------------- gemm2: out[b,i,d] = (P . x) / l ----------------
// grid 512 = 8 batches x 16 i-tiles x 4 d-tiles ; 256 threads = 4 waves
__global__ __launch_bounds__(256, 3) void gemm2_kernel(const unsigned short* __restrict__ P,
                                                       const unsigned short* __restrict__ xt,
                                                       const float* __restrict__ l,
                                                       float* __restrict__ out) {
  const int b  = blockIdx.x & 7;
  const int t  = blockIdx.x >> 3;
  const int i0 = (t & 15) * 128;
  const int n0 = (t >> 4) * 128;
  const int tid  = threadIdx.x;
  const int w    = tid >> 6;
  const int lane = tid & 63;
  const int ln   = lane & 31;
  const int half = lane >> 5;

  __shared__ __align__(16) unsigned short sA[8192];
  __shared__ __align__(16) unsigned short sB[8192];
  __shared__ float sl[128];

  const unsigned short* Ag = P  + (long)b * SEQ * SEQ + (long)i0 * SEQ;
  const unsigned short* Bg = xt + (long)b * DIM * SEQ + (long)n0 * SEQ;

  if (tid < 128) sl[tid] = l[b * SEQ + i0 + tid];

  floatx16 acc[2][2];
#pragma unroll
  for (int mt = 0; mt < 2; ++mt)
#pragma unroll
    for (int nt = 0; nt < 2; ++nt)
#pragma unroll
      for (int i = 0; i < 16; ++i) acc[mt][nt][i] = 0.f;

  const int r0 = (w >> 1) * 64;
  const int c0 = (w & 1) * 64;

  for (int kc = 0; kc < 32; ++kc) {
#pragma unroll
    for (int k = 0; k < 4; ++k) {
      int u = tid + k * 256;
      int row = u >> 3, c = u & 7;
      int gc = (c ^ (row & 7)) * 8;
      gld_lds16(Ag + (long)row * SEQ + kc * 64 + gc, sA + u * 8);
      gld_lds16(Bg + (long)row * SEQ + kc * 64 + gc, sB + u * 8);
    }
    __syncthreads();
#pragma unroll
    for (int kk = 0; kk < 4; ++kk) {
      const int cc = kk * 2 + half;
      short8 af[2], bf[2];
#pragma unroll
      for (int mt = 0; mt < 2; ++mt) {
        int r = r0 + mt * 32 + ln;
        af[mt] = ld_frag8(sA + r * 64 + (cc ^ (r & 7)) * 8);
      }
#pragma unroll
      for (int nt = 0; nt < 2; ++nt) {
        int r = c0 + nt * 32 + ln;
        bf[nt] = ld_frag8(sB + r * 64 + (cc ^ (r & 7)) * 8);
      }
#pragma unroll
      for (int mt = 0; mt < 2; ++mt)
#pragma unroll
        for (int nt = 0; nt < 2; ++nt)
          acc[mt][nt] = __builtin_amdgcn_mfma_f32_32x32x16_bf16(af[mt], bf[nt], acc[mt][nt], 0, 0, 0);
    }
    __syncthreads();
  }

  // epilogue: divide by l, direct fp32 stores (128B per 32-lane half-instruction)
  float* outb = out + (long)b * SEQ * DIM;
#pragma unroll
  for (int mt = 0; mt < 2; ++mt)
#pragma unroll
    for (int r = 0; r < 16; ++r) {
      const int row = r0 + mt * 32 + (r & 3) + 8 * (r >> 2) + 4 * half;
      const float inv = 1.0f / sl[row];
#pragma unroll
      for (int nt = 0; nt < 2; ++nt) {
        const int col = c0 + nt * 32 + ln;
        outb[(long)(i0 + row) * DIM + n0 + col] = acc[mt][nt][r] * inv;
      }
    }
}

extern "C" void kernel_launch(void* const* d_in, const int* in_sizes, int n_in,
                              void* d_out, int out_size, void* d_ws, size_t ws_size,
                              hipStream_t stream) {
  const float* x = (const float*)d_in[0];
  float* outp = (float*)d_out;

  unsigned short* xn = (unsigned short*)d_ws;                        // 16.78 MB
  unsigned short* xt = xn + (size_t)BATCH * SEQ * DIM;               // 16.78 MB
  unsigned short* Pw = xt + (size_t)BATCH * SEQ * DIM;               // 67.1 MB
  float*          lw = (float*)(Pw + (size_t)BATCH * SEQ * SEQ);     // 64 KB

  prep_kernel  <<<BATCH * (SEQ / 32), 256, 0, stream>>>(x, xn, xt);
  gemm1_kernel <<<BATCH * 16 * 16,    256, 0, stream>>>(xn, Pw);
  rowsum_kernel<<<BATCH * SEQ / 4,    256, 0, stream>>>(Pw, lw);
  gemm2_kernel <<<BATCH * 16 * 4,     256, 0, stream>>>(Pw, xt, lw, outp);
}